// Round 14
// baseline (188.539 us; speedup 1.0000x reference)
//
#include <hip/hip_runtime.h>
#include <math.h>

#define DNUM 1024
#define CNUM 32000
#define NT 1024              // 16 waves/block
#define GRID DNUM            // 1 row/block -> 1 block/CU (LDS-bound), 4 seq rounds
#define KC 4                 // coarse bins (1.35 sigma'), span [-5s', +0.4s'] shifted
#define KF 16                // fine bins (0.084 sigma')
#define NQ (CNUM / 4)        // 8000 4-class groups
#define NFULL (NQ / NT)      // 7
#define TAILN (NQ - NFULL*NT) // 832

#define L2E 1.4426950408889634f
#define LN2 0.6931471805599453f

typedef _Float16 h2f __attribute__((ext_vector_type(2)));

__device__ __forceinline__ unsigned pack16(float a, float b) {
    h2f v; v.x = (_Float16)a; v.y = (_Float16)b;
    return __builtin_bit_cast(unsigned, v);
}

__device__ __forceinline__ float wave_red_sum(float v) {
    #pragma unroll
    for (int o = 32; o > 0; o >>= 1) v += __shfl_down(v, o, 64);
    return v;
}

// One block = 1 row. Pass 1 streams e1/e3 once (L2-resident), computes all
// fp32 moments + a coarse 4-bin private-LDS e2 histogram, AND caches
// (e1,e2) as packed fp16 pairs in LDS (125 KB). Pass 2 never touches global
// memory or exp2: it re-reads the fp16 cache (ds_read_b128, 4 classes/read),
// accumulates gap = |e2 - c*e1| (c = U2/U1; akl is scale-invariant in gap),
// and resolves the 0.5-cumsum crossing with 16 fine bins located via
// e2-space compares (log2 only in the ~1% in-window branch; fine bins are a
// tiny shared array updated by rare atomics). Secant interpolation at the
// crossing. Logits in log2 domain, shift 4.5*sigma' (fp16-safe).
__global__ __launch_bounds__(NT, 4) void akl_rows(
    const float* __restrict__ h1, const float* __restrict__ e1,
    const float* __restrict__ h3, const float* __restrict__ e3,
    float* __restrict__ out)
{
    const int tid  = threadIdx.x;
    const int lane = tid & 63, wid = tid >> 6;   // 16 waves
    const int row  = blockIdx.x;

    __shared__ __align__(16) unsigned cacheW[CNUM];  // 125 KB fp16 (e1,e2) pairs
    __shared__ float hist[KC*NT];                    // 16 KB coarse private slots
    __shared__ float red[64];
    __shared__ float shCS[KC];
    __shared__ float fineP[KF], fineG[KF];
    __shared__ float shA[8];  // c, thr, fkl, rkl, w_lo, w_hi, loS, icwF

    // Row coefficients, log2 domain; shift = 4.5*sigma' keeps exp2 in fp16 range
    const float a1L = h1[2*row] * L2E, b1L = h1[2*row+1] * L2E;
    const float a2L = h3[2*row] * L2E, b2L = h3[2*row+1] * L2E;
    const float s1g = fmaxf(sqrtf(a1L*a1L + b1L*b1L), 1e-6f);
    const float s2g = fmaxf(sqrtf(a2L*a2L + b2L*b2L), 1e-6f);
    const float sh1 = 4.5f * s1g, sh2 = 4.5f * s2g;
    const float icwC = 1.0f / (1.35f * s2g);
    const float c0C  = 5.0f / 1.35f;     // grid starts at -5*s2g (shifted coords)

    for (int i = tid; i < KC*NT; i += NT) hist[i] = 0.f;
    __syncthreads();                                                   // B0

    const float4* __restrict__ E1 = (const float4*)e1;
    const float4* __restrict__ E3 = (const float4*)e3;

    // ================= Pass 1: moments + coarse hist + fp16 cache ==========
    float U1 = 0.f, U2 = 0.f, S1 = 0.f, S2 = 0.f;
    auto body1 = [&](int j) {
        float4 A0 = E1[2*j], A1 = E1[2*j+1], B0 = E3[2*j], B1 = E3[2*j+1];
        float x1[4]={A0.x,A0.z,A1.x,A1.z}, y1[4]={A0.y,A0.w,A1.y,A1.w};
        float x3[4]={B0.x,B0.z,B1.x,B1.z}, y3[4]={B0.y,B0.w,B1.y,B1.w};
        unsigned pk[4];
        #pragma unroll
        for (int k = 0; k < 4; k++) {
            float l1s = fmaf(a1L, x1[k], fmaf(b1L, y1[k], -sh1));
            float l2s = fmaf(a2L, x3[k], fmaf(b2L, y3[k], -sh2));
            float e1v = __builtin_amdgcn_exp2f(l1s);
            float e2v = __builtin_amdgcn_exp2f(l2s);
            float dp  = l2s - l1s;               // corrected post-pass
            U1 += e1v; U2 += e2v;
            S1 = fmaf(e1v, dp, S1);
            S2 = fmaf(e2v, dp, S2);
            int cb = (int)fmaf(l2s, icwC, c0C);
            cb = min(KC-1, max(0, cb));
            hist[cb*NT + tid] += e2v;            // private slot: no race
            pk[k] = pack16(e1v, e2v);
        }
        uint4 q; q.x = pk[0]; q.y = pk[1]; q.z = pk[2]; q.w = pk[3];
        ((uint4*)cacheW)[j] = q;                 // one ds_write_b128
    };
    #pragma unroll 1
    for (int it = 0; it < NFULL; ++it) body1(it*NT + tid);
    if (tid < TAILN) body1(NFULL*NT + tid);

    {
        float u1 = wave_red_sum(U1), u2 = wave_red_sum(U2);
        float s1 = wave_red_sum(S1), s2 = wave_red_sum(S2);
        if (lane == 0) {
            red[wid*4+0] = u1; red[wid*4+1] = u2;
            red[wid*4+2] = s1; red[wid*4+3] = s2;
        }
    }
    __syncthreads();                                                   // B1

    // ---- Reduce coarse histogram (waves 0..3), zero fine arrays (wave 4) ----
    if (wid < KC) {
        float s = 0.f;
        #pragma unroll
        for (int t = 0; t < NT/64; t++) s += hist[wid*NT + lane + t*64];
        s = wave_red_sum(s);
        if (lane == 0) shCS[wid] = s;
    }
    if (tid >= 256 && tid < 256 + KF) { fineP[tid-256] = 0.f; fineG[tid-256] = 0.f; }
    __syncthreads();                                                   // B2

    // ---- Row params + crossing cell -> e2-space window (one thread) ----
    if (tid == 0) {
        float U1s = 0, U2s = 0, S1s = 0, S2s = 0;
        for (int w = 0; w < NT/64; w++) {
            U1s += red[w*4+0]; U2s += red[w*4+1];
            S1s += red[w*4+2]; S2s += red[w*4+3];
        }
        float dmh = sh2 - sh1;
        S1s += dmh * U1s;                        // exact shift correction
        S2s += dmh * U2s;
        float M1 = sh1 + __builtin_amdgcn_logf(U1s);
        float M2 = sh2 + __builtin_amdgcn_logf(U2s);
        float delta = M2 - M1;
        float thr = 0.5f * U2s;
        float S = 0.f; int bsel = KC-1;
        for (int i = 0; i < KC; i++) {
            float m = shCS[i];
            if (S + m >= thr) { bsel = i; break; }
            S += m;
        }
        float loS = s2g * fmaf(1.35f, (float)bsel, -5.0f);  // shifted coords
        shA[0] = U2s / U1s;                      // c
        shA[1] = thr;
        shA[2] = LN2 * (S2s/U2s - delta);        // fkl
        shA[3] = LN2 * (delta - S1s/U1s);        // rkl
        shA[4] = __builtin_amdgcn_exp2f(loS);                  // w_lo
        shA[5] = __builtin_amdgcn_exp2f(loS + 1.35f*s2g);      // w_hi
        shA[6] = loS;
        shA[7] = (float)KF / (1.35f * s2g);      // icwF
    }
    __syncthreads();                                                   // B3

    // ================= Pass 2: LDS-only gap stats + fine window =============
    const float cc = shA[0], w_lo = shA[4], w_hi = shA[5];
    const float loS = shA[6], icwF = shA[7];
    float gt = 0.f, Gp = 0.f, Pp = 0.f;
    auto body2 = [&](int g) {
        uint4 q = ((const uint4*)cacheW)[g];     // one ds_read_b128, 4 classes
        unsigned wv[4] = {q.x, q.y, q.z, q.w};
        #pragma unroll
        for (int k = 0; k < 4; k++) {
            h2f hv = __builtin_bit_cast(h2f, wv[k]);
            float e1f = (float)hv.x, e2f = (float)hv.y;
            float gap = fabsf(fmaf(-cc, e1f, e2f));
            gt += gap;
            bool below = e2f < w_lo;
            Pp += below ? e2f : 0.f;
            Gp += below ? gap : 0.f;
            if (!below && e2f < w_hi) {          // ~1% of elements
                float lg = __builtin_amdgcn_logf(e2f);
                int fb = (int)((lg - loS) * icwF);
                fb = min(KF-1, max(0, fb));
                unsafeAtomicAdd(&fineP[fb], e2f);
                unsafeAtomicAdd(&fineG[fb], gap);
            }
        }
    };
    #pragma unroll 1
    for (int it = 0; it < NFULL; ++it) body2(it*NT + tid);
    if (tid < TAILN) body2(NFULL*NT + tid);

    {
        float a = wave_red_sum(gt), b = wave_red_sum(Gp), c2 = wave_red_sum(Pp);
        if (lane == 0) { red[wid*3+0] = a; red[wid*3+1] = b; red[wid*3+2] = c2; }
    }
    __syncthreads();                                                   // B4

    // ---- Walk fine bins, secant-interpolate 0.5 crossing, output ----
    if (tid == 0) {
        float gts = 0, Gps = 0, Pps = 0;
        for (int w = 0; w < NT/64; w++) {
            gts += red[w*3+0]; Gps += red[w*3+1]; Pps += red[w*3+2];
        }
        float thr = shA[1], fkl = shA[2], rkl = shA[3];
        float S = Pps, G = Gps;
        bool done = false;
        #pragma unroll
        for (int i = 0; i < KF; i++) {
            if (!done) {
                float p = fineP[i], g = fineG[i];
                float ns = S + p;
                if (ns >= thr) {
                    float f = (thr - S) / fmaxf(p, 1e-30f);
                    f = fminf(fmaxf(f, 0.f), 1.f);
                    G += f * g;
                    done = true;
                } else { S = ns; G += g; }
            }
        }
        float gl = G;                    // g_tail (unnormalized: scale cancels)
        float gh = gts - gl;             // g_head
        float akl = (gh*fkl + gl*rkl) / gts;
        unsafeAtomicAdd(out, akl * (1.0f/(float)DNUM));
    }
}

extern "C" void kernel_launch(void* const* d_in, const int* in_sizes, int n_in,
                              void* d_out, int out_size, void* d_ws, size_t ws_size,
                              hipStream_t stream) {
    const float* h1 = (const float*)d_in[0];
    const float* e1 = (const float*)d_in[1];
    const float* h3 = (const float*)d_in[2];
    const float* e3 = (const float*)d_in[3];
    hipMemsetAsync(d_out, 0, sizeof(float), stream);   // capture-safe
    akl_rows<<<GRID, NT, 0, stream>>>(h1, e1, h3, e3, (float*)d_out);
}

// Round 15
// 132.955 us; speedup vs baseline: 1.4181x; 1.4181x over previous
//
#include <hip/hip_runtime.h>
#include <math.h>

#define DNUM 1024
#define CNUM 32000
#define NT 512             // 8 waves/block
#define R 2                // rows per block
#define GRID (DNUM / R)    // 512 blocks -> 2 resident blocks/CU (grid-limited)
#define KC 8               // coarse bins (0.675 sigma each)
#define KF 8               // fine bins   (0.084 sigma each)
#define NQ (CNUM / 4)      // 8000 4-class chunks
#define NFULL (NQ / NT)    // 15 full iterations
#define TAILN (NQ - NFULL*NT) // 320

#define L2E 1.4426950408889634f
#define LN2 0.6931471805599453f

__device__ __forceinline__ float wave_red_sum(float v) {
    #pragma unroll
    for (int o = 32; o > 0; o >>= 1) v += __shfl_down(v, o, 64);
    return v;
}

// One block = 2 rows, two streaming passes over L2-resident e1/e3.
// P1: per-thread-private LDS histogram slots split across 4 distinct arrays
// (row x class-pair) -> no atomics, no races, conflict-free, independent
// read-add-write chains. P2: gap stats in registers; the rare (~0.5%)
// crossing-cell elements go to a tiny 32-entry shared fine histogram via
// unsafeAtomicAdd (negligible under the measured LDS-atomic cost law).
// Secant interpolation at the 0.5-cumsum crossing. Gap unnormalized
// (|e2 - c*e1|, c=U2/U1; akl is scale-invariant in gap). Logits in log2
// domain with the softmax shift folded into the FMA chain.
__global__ __launch_bounds__(NT, 4) void akl_rows(
    const float* __restrict__ h1, const float* __restrict__ e1,
    const float* __restrict__ h3, const float* __restrict__ e3,
    float* __restrict__ out)
{
    const int tid  = threadIdx.x;
    const int lane = tid & 63, wid = tid >> 6;   // 8 waves
    const int row0 = blockIdx.x * R;

    __shared__ float hC0[KC*NT];   // row0 classes {0,1}
    __shared__ float hC1[KC*NT];   // row0 classes {2,3}
    __shared__ float hC2[KC*NT];   // row1 classes {0,1}
    __shared__ float hC3[KC*NT];   // row1 classes {2,3}
    __shared__ float red[48];
    __shared__ float shCS[R*KC];
    __shared__ float fineP[R*KF], fineG[R*KF];
    __shared__ float shA[R][7];    // c, thr, fkl, rkl, icwF, c0Fs, Spre

    // Per-row coefficients, log2 domain
    float a1L[R], b1L[R], a2L[R], b2L[R], mh1L[R], mh2L[R], icwC[R], c0C[R];
    #pragma unroll
    for (int r = 0; r < R; r++) {
        a1L[r] = h1[2*(row0+r)] * L2E; b1L[r] = h1[2*(row0+r)+1] * L2E;
        a2L[r] = h3[2*(row0+r)] * L2E; b2L[r] = h3[2*(row0+r)+1] * L2E;
        mh1L[r] = 6.0f * (fabsf(a1L[r]) + fabsf(b1L[r]));   // safe shift
        mh2L[r] = 6.0f * (fabsf(a2L[r]) + fabsf(b2L[r]));
        float sp = fmaxf(sqrtf(a2L[r]*a2L[r] + b2L[r]*b2L[r]), 1e-6f);
        icwC[r] = 1.0f / (0.675f * sp);          // span [-0.5s, +4.9s], 8 cells
        c0C[r] = 0.5f/0.675f + mh2L[r]*icwC[r];  // cb=(int)(l2s*icwC + c0C)
    }
    for (int i = tid; i < KC*NT; i += NT) {
        hC0[i] = 0.f; hC1[i] = 0.f; hC2[i] = 0.f; hC3[i] = 0.f;
    }
    if (tid < R*KF) { fineP[tid] = 0.f; fineG[tid] = 0.f; }
    __syncthreads();                                                   // B0

    const float4* __restrict__ E1 = (const float4*)e1;
    const float4* __restrict__ E3 = (const float4*)e3;

    // ================= Pass 1: moments + coarse split-array partition =======
    float U1[R] = {0,0}, S1p[R] = {0,0}, S2p[R] = {0,0};
    auto body1 = [&](int j) {
        float4 A0 = E1[2*j], A1 = E1[2*j+1], B0 = E3[2*j], B1 = E3[2*j+1];
        float x1[4]={A0.x,A0.z,A1.x,A1.z}, y1[4]={A0.y,A0.w,A1.y,A1.w};
        float x3[4]={B0.x,B0.z,B1.x,B1.z}, y3[4]={B0.y,B0.w,B1.y,B1.w};
        #pragma unroll
        for (int r = 0; r < R; r++) {
            #pragma unroll
            for (int k = 0; k < 4; k++) {
                float l1s = fmaf(a1L[r], x1[k], fmaf(b1L[r], y1[k], -mh1L[r]));
                float l2s = fmaf(a2L[r], x3[k], fmaf(b2L[r], y3[k], -mh2L[r]));
                float e1v = __builtin_amdgcn_exp2f(l1s);
                float e2v = __builtin_amdgcn_exp2f(l2s);
                float dps = l2s - l1s;              // corrected post-pass
                U1[r] += e1v;
                S1p[r] = fmaf(e1v, dps, S1p[r]);
                S2p[r] = fmaf(e2v, dps, S2p[r]);
                int cb = (int)fmaf(l2s, icwC[r], c0C[r]);
                cb = min(KC-1, max(0, cb));
                float* H = (r == 0) ? ((k < 2) ? hC0 : hC1)
                                    : ((k < 2) ? hC2 : hC3);
                H[cb*NT + tid] += e2v;              // private: no race
            }
        }
    };
    #pragma unroll 1
    for (int it = 0; it < NFULL; ++it) body1(it*NT + tid);
    if (tid < TAILN) body1(NFULL*NT + tid);

    #pragma unroll
    for (int r = 0; r < R; r++) {
        float u = wave_red_sum(U1[r]);
        float s1 = wave_red_sum(S1p[r]);
        float s2 = wave_red_sum(S2p[r]);
        if (lane == 0) {
            red[wid*6 + r*3 + 0] = u;
            red[wid*6 + r*3 + 1] = s1;
            red[wid*6 + r*3 + 2] = s2;
        }
    }
    __syncthreads();                                                   // B1

    // ---- Reduce coarse histogram: 16 groups (r x bin) x 32 lanes ----
    {
        int grp = tid >> 5, l32 = tid & 31;        // grp = r*KC + bin
        int r = grp >> 3, b = grp & 7;
        const float* Ha = r ? hC2 : hC0;
        const float* Hb = r ? hC3 : hC1;
        float s = 0.f;
        #pragma unroll
        for (int t = 0; t < NT/32; t++) {
            s += Ha[b*NT + l32 + t*32] + Hb[b*NT + l32 + t*32];
        }
        #pragma unroll
        for (int o = 16; o > 0; o >>= 1) s += __shfl_down(s, o, 64);
        if (l32 == 0) shCS[grp] = s;
    }
    __syncthreads();                                                   // B2

    // ---- Row params + coarse crossing cell (one thread per row) ----
    if (tid < R) {
        const int r = tid;
        float U1s = 0, S1s = 0, S2s = 0;
        for (int w = 0; w < 8; w++) {
            U1s += red[w*6 + r*3 + 0];
            S1s += red[w*6 + r*3 + 1];
            S2s += red[w*6 + r*3 + 2];
        }
        float U2s = 0.f;
        #pragma unroll
        for (int i = 0; i < KC; i++) U2s += shCS[r*KC + i];
        float mh1r = r ? mh1L[1] : mh1L[0];
        float mh2r = r ? mh2L[1] : mh2L[0];
        float a2r = r ? a2L[1] : a2L[0];
        float b2r = r ? b2L[1] : b2L[0];
        float dmh = mh2r - mh1r;
        S1s += dmh * U1s;                        // exact shift correction
        S2s += dmh * U2s;
        float M1 = mh1r + __builtin_amdgcn_logf(U1s);
        float M2 = mh2r + __builtin_amdgcn_logf(U2s);
        float delta = M2 - M1;
        float thr = 0.5f * U2s;
        float S = 0.f; int bsel = KC-1;
        for (int i = 0; i < KC; i++) {
            float m = shCS[r*KC + i];
            if (S + m >= thr) { bsel = i; break; }
            S += m;
        }
        float sp = fmaxf(sqrtf(a2r*a2r + b2r*b2r), 1e-6f);
        float wc  = 0.675f * sp;
        float loS_s = fmaf((float)bsel, wc, -0.5f*sp) - mh2r;  // shifted space
        float icwF = (float)KF / wc;
        shA[r][0] = U2s / U1s;                   // c (gap scale fold)
        shA[r][1] = thr;
        shA[r][2] = LN2 * (S2s/U2s - delta);     // fkl
        shA[r][3] = LN2 * (delta - S1s/U1s);     // rkl
        shA[r][4] = icwF;
        shA[r][5] = -loS_s * icwF;               // c0Fs: t=l2s*icwF+c0Fs
        shA[r][6] = S;                           // Spre (unnorm prefix below cell)
    }
    __syncthreads();                                                   // B3

    // ================= Pass 2: gap stats + rare-atomic fine bins ============
    float cR[R], icwFl[R], c0Fl[R];
    #pragma unroll
    for (int r = 0; r < R; r++) {
        cR[r] = shA[r][0]; icwFl[r] = shA[r][4]; c0Fl[r] = shA[r][5];
    }
    float gt[R] = {0,0}, Gpre[R] = {0,0};
    auto body2 = [&](int j) {
        float4 A0 = E1[2*j], A1 = E1[2*j+1], B0 = E3[2*j], B1 = E3[2*j+1];
        float x1[4]={A0.x,A0.z,A1.x,A1.z}, y1[4]={A0.y,A0.w,A1.y,A1.w};
        float x3[4]={B0.x,B0.z,B1.x,B1.z}, y3[4]={B0.y,B0.w,B1.y,B1.w};
        #pragma unroll
        for (int r = 0; r < R; r++) {
            #pragma unroll
            for (int k = 0; k < 4; k++) {
                float l1s = fmaf(a1L[r], x1[k], fmaf(b1L[r], y1[k], -mh1L[r]));
                float l2s = fmaf(a2L[r], x3[k], fmaf(b2L[r], y3[k], -mh2L[r]));
                float e1v = __builtin_amdgcn_exp2f(l1s);
                float e2v = __builtin_amdgcn_exp2f(l2s);
                float gap = fabsf(fmaf(e1v, -cR[r], e2v));
                gt[r] += gap;
                float t = fmaf(l2s, icwFl[r], c0Fl[r]);
                Gpre[r] += (t < 0.f) ? gap : 0.f;
                if (t >= 0.f && t < (float)KF) {    // ~0.5% of elements
                    int fb = (int)t;
                    unsafeAtomicAdd(&fineP[r*KF + fb], e2v);
                    unsafeAtomicAdd(&fineG[r*KF + fb], gap);
                }
            }
        }
    };
    #pragma unroll 1
    for (int it = 0; it < NFULL; ++it) body2(it*NT + tid);
    if (tid < TAILN) body2(NFULL*NT + tid);

    #pragma unroll
    for (int r = 0; r < R; r++) {
        float a = wave_red_sum(gt[r]);
        float b = wave_red_sum(Gpre[r]);
        if (lane == 0) { red[wid*4 + r*2 + 0] = a; red[wid*4 + r*2 + 1] = b; }
    }
    __syncthreads();                                                   // B4

    // ---- Walk fine bins, secant-interpolate 0.5 crossing, output ----
    if (tid < R) {
        const int r = tid;
        float gts = 0, Gp = 0;
        for (int w = 0; w < 8; w++) {
            gts += red[w*4 + r*2 + 0];
            Gp  += red[w*4 + r*2 + 1];
        }
        float thr = shA[r][1], fkl = shA[r][2], rkl = shA[r][3];
        float S = shA[r][6], G = Gp;
        bool done = false;
        #pragma unroll
        for (int i = 0; i < KF; i++) {
            if (!done) {
                float p = fineP[r*KF + i], g = fineG[r*KF + i];
                float ns = S + p;
                if (ns >= thr) {
                    float f = (thr - S) / fmaxf(p, 1e-30f);
                    f = fminf(fmaxf(f, 0.f), 1.f);
                    G += f * g;
                    done = true;
                } else { S = ns; G += g; }
            }
        }
        float gl = G;                    // g_tail (unnormalized: scale cancels)
        float gh = gts - gl;             // g_head
        float akl = (gh*fkl + gl*rkl) / gts;
        unsafeAtomicAdd(out, akl * (1.0f/(float)DNUM));
    }
}

extern "C" void kernel_launch(void* const* d_in, const int* in_sizes, int n_in,
                              void* d_out, int out_size, void* d_ws, size_t ws_size,
                              hipStream_t stream) {
    const float* h1 = (const float*)d_in[0];
    const float* e1 = (const float*)d_in[1];
    const float* h3 = (const float*)d_in[2];
    const float* e3 = (const float*)d_in[3];
    hipMemsetAsync(d_out, 0, sizeof(float), stream);   // capture-safe
    akl_rows<<<GRID, NT, 0, stream>>>(h1, e1, h3, e3, (float*)d_out);
}

// Round 16
// 104.942 us; speedup vs baseline: 1.7966x; 1.2669x over previous
//
#include <hip/hip_runtime.h>
#include <math.h>

#define DNUM 1024
#define CNUM 32000
#define NT 512             // 8 waves/block
#define R 2                // rows per block
#define GRID (DNUM / R)    // 512 blocks -> 2 resident blocks/CU (grid-limited)
#define KC 8               // coarse bins (0.675 sigma each)
#define KF 8               // fine bins   (0.084 sigma each)
#define NQ (CNUM / 4)      // 8000 4-class chunks
#define NFULL (NQ / NT)    // 15 full iterations
#define TAILN (NQ - NFULL*NT) // 320

#define L2E 1.4426950408889634f
#define LN2 0.6931471805599453f

__device__ __forceinline__ float wave_red_sum(float v) {
    #pragma unroll
    for (int o = 32; o > 0; o >>= 1) v += __shfl_down(v, o, 64);
    return v;
}

// One block = 2 rows, two streaming passes over L2-resident e1/e3.
// Histograms: per-thread-private LDS slots, SPLIT ACROSS 4 DISTINCT __shared__
// ARRAYS (row x class-pair) so the compiler can interleave the read-add-write
// chains (no may-alias serialization, no atomics anywhere in hot loops —
// r15 showed even rarely-executed DS-atomics poison the load pipelining).
// Logit shift folded into the FMA chain; Sigma e*d accumulated shifted and
// corrected exactly post-pass. Secant interpolation at the 0.5 crossing.
__global__ __launch_bounds__(NT, 4) void akl_rows(
    const float* __restrict__ h1, const float* __restrict__ e1,
    const float* __restrict__ h3, const float* __restrict__ e3,
    float* __restrict__ out)
{
    const int tid  = threadIdx.x;
    const int lane = tid & 63, wid = tid >> 6;   // 8 waves
    const int row0 = blockIdx.x * R;

    __shared__ float hC0[KC*NT];   // P1: row0 classes {0,1} | P2: fine e2  row0
    __shared__ float hC1[KC*NT];   // P1: row0 classes {2,3} | P2: fine e2  row1
    __shared__ float hC2[KC*NT];   // P1: row1 classes {0,1} | P2: fine gap row0
    __shared__ float hC3[KC*NT];   // P1: row1 classes {2,3} | P2: fine gap row1
    __shared__ float red[48];
    __shared__ float shCS[R*KC];
    __shared__ float shFP[R*KF], shFG[R*KF];
    __shared__ float shA[R][8];    // iU1,iU2,thr,fkl,rkl,icwF,c0Fs,Spre

    // Per-row coefficients, log2 domain
    float a1L[R], b1L[R], a2L[R], b2L[R], mh1L[R], mh2L[R], icwC[R], c0C[R];
    #pragma unroll
    for (int r = 0; r < R; r++) {
        a1L[r] = h1[2*(row0+r)] * L2E; b1L[r] = h1[2*(row0+r)+1] * L2E;
        a2L[r] = h3[2*(row0+r)] * L2E; b2L[r] = h3[2*(row0+r)+1] * L2E;
        mh1L[r] = 6.0f * (fabsf(a1L[r]) + fabsf(b1L[r]));   // safe shift
        mh2L[r] = 6.0f * (fabsf(a2L[r]) + fabsf(b2L[r]));
        float sp = fmaxf(sqrtf(a2L[r]*a2L[r] + b2L[r]*b2L[r]), 1e-6f);
        icwC[r] = 1.0f / (0.675f * sp);          // span [-0.5s, +4.9s], 8 cells
        c0C[r] = 0.5f/0.675f + mh2L[r]*icwC[r];  // cb=(int)(l2s*icwC + c0C)
    }
    for (int i = tid; i < KC*NT; i += NT) {
        hC0[i] = 0.f; hC1[i] = 0.f; hC2[i] = 0.f; hC3[i] = 0.f;
    }
    __syncthreads();                                                   // B0

    const float4* __restrict__ E1 = (const float4*)e1;
    const float4* __restrict__ E3 = (const float4*)e3;

    // ================= Pass 1: moments + coarse split-array partition =======
    float U1[R] = {0,0}, S1p[R] = {0,0}, S2p[R] = {0,0};
    auto body1 = [&](int j) {
        float4 A0 = E1[2*j], A1 = E1[2*j+1], B0 = E3[2*j], B1 = E3[2*j+1];
        float x1[4]={A0.x,A0.z,A1.x,A1.z}, y1[4]={A0.y,A0.w,A1.y,A1.w};
        float x3[4]={B0.x,B0.z,B1.x,B1.z}, y3[4]={B0.y,B0.w,B1.y,B1.w};
        #pragma unroll
        for (int r = 0; r < R; r++) {
            #pragma unroll
            for (int k = 0; k < 4; k++) {
                float l1s = fmaf(a1L[r], x1[k], fmaf(b1L[r], y1[k], -mh1L[r]));
                float l2s = fmaf(a2L[r], x3[k], fmaf(b2L[r], y3[k], -mh2L[r]));
                float e1v = __builtin_amdgcn_exp2f(l1s);
                float e2v = __builtin_amdgcn_exp2f(l2s);
                float dps = l2s - l1s;              // corrected post-pass
                U1[r] += e1v;
                S1p[r] = fmaf(e1v, dps, S1p[r]);
                S2p[r] = fmaf(e2v, dps, S2p[r]);
                int cb = (int)fmaf(l2s, icwC[r], c0C[r]);
                cb = min(KC-1, max(0, cb));
                float* H = (r == 0) ? ((k < 2) ? hC0 : hC1)
                                    : ((k < 2) ? hC2 : hC3);
                H[cb*NT + tid] += e2v;              // private: no race
            }
        }
    };
    #pragma unroll 1
    for (int it = 0; it < NFULL; ++it) body1(it*NT + tid);
    if (tid < TAILN) body1(NFULL*NT + tid);

    #pragma unroll
    for (int r = 0; r < R; r++) {
        float u = wave_red_sum(U1[r]);
        float s1 = wave_red_sum(S1p[r]);
        float s2 = wave_red_sum(S2p[r]);
        if (lane == 0) {
            red[wid*6 + r*3 + 0] = u;
            red[wid*6 + r*3 + 1] = s1;
            red[wid*6 + r*3 + 2] = s2;
        }
    }
    __syncthreads();                                                   // B1

    // ---- Reduce coarse histogram: 16 groups (r x bin) x 32 lanes ----
    {
        int grp = tid >> 5, l32 = tid & 31;        // grp = r*KC + bin
        int r = grp >> 3, b = grp & 7;
        const float* Ha = r ? hC2 : hC0;
        const float* Hb = r ? hC3 : hC1;
        float s = 0.f;
        #pragma unroll
        for (int t = 0; t < NT/32; t++) {
            s += Ha[b*NT + l32 + t*32] + Hb[b*NT + l32 + t*32];
        }
        #pragma unroll
        for (int o = 16; o > 0; o >>= 1) s += __shfl_down(s, o, 64);
        if (l32 == 0) shCS[grp] = s;
    }
    __syncthreads();                                                   // B2

    // ---- Row params + coarse crossing cell (one thread per row) ----
    if (tid < R) {
        const int r = tid;
        float U1s = 0, S1s = 0, S2s = 0;
        for (int w = 0; w < 8; w++) {
            U1s += red[w*6 + r*3 + 0];
            S1s += red[w*6 + r*3 + 1];
            S2s += red[w*6 + r*3 + 2];
        }
        float U2s = 0.f;
        #pragma unroll
        for (int i = 0; i < KC; i++) U2s += shCS[r*KC + i];
        float mh1r = r ? mh1L[1] : mh1L[0];
        float mh2r = r ? mh2L[1] : mh2L[0];
        float a2r = r ? a2L[1] : a2L[0];
        float b2r = r ? b2L[1] : b2L[0];
        float dmh = mh2r - mh1r;
        S1s += dmh * U1s;                        // exact shift correction
        S2s += dmh * U2s;
        float M1 = mh1r + __builtin_amdgcn_logf(U1s);
        float M2 = mh2r + __builtin_amdgcn_logf(U2s);
        float delta = M2 - M1;
        float thr = 0.5f * U2s;
        float S = 0.f; int bsel = KC-1;
        for (int i = 0; i < KC; i++) {
            float m = shCS[r*KC + i];
            if (S + m >= thr) { bsel = i; break; }
            S += m;
        }
        float sp = fmaxf(sqrtf(a2r*a2r + b2r*b2r), 1e-6f);
        float wc  = 0.675f * sp;
        float loS_s = fmaf((float)bsel, wc, -0.5f*sp) - mh2r;  // shifted space
        float icwF = (float)KF / wc;
        shA[r][0] = U2s / U1s;                   // c (gap scale fold)
        shA[r][1] = thr;
        shA[r][2] = LN2 * (S2s/U2s - delta);     // fkl
        shA[r][3] = LN2 * (delta - S1s/U1s);     // rkl
        shA[r][4] = icwF;
        shA[r][5] = -loS_s * icwF;               // c0Fs: t=l2s*icwF+c0Fs
        shA[r][6] = S;                           // Spre (unnorm prefix below cell)
    }
    // re-zero for fine pass
    for (int i = tid; i < KF*NT; i += NT) {
        hC0[i] = 0.f; hC1[i] = 0.f; hC2[i] = 0.f; hC3[i] = 0.f;
    }
    __syncthreads();                                                   // B3

    // ================= Pass 2: gap stats + fine split-array partition =======
    float cR[R], icwFl[R], c0Fl[R];
    #pragma unroll
    for (int r = 0; r < R; r++) {
        cR[r] = shA[r][0]; icwFl[r] = shA[r][4]; c0Fl[r] = shA[r][5];
    }
    float gt[R] = {0,0}, Gpre[R] = {0,0};
    auto body2 = [&](int j) {
        float4 A0 = E1[2*j], A1 = E1[2*j+1], B0 = E3[2*j], B1 = E3[2*j+1];
        float x1[4]={A0.x,A0.z,A1.x,A1.z}, y1[4]={A0.y,A0.w,A1.y,A1.w};
        float x3[4]={B0.x,B0.z,B1.x,B1.z}, y3[4]={B0.y,B0.w,B1.y,B1.w};
        #pragma unroll
        for (int r = 0; r < R; r++) {
            #pragma unroll
            for (int k = 0; k < 4; k++) {
                float l1s = fmaf(a1L[r], x1[k], fmaf(b1L[r], y1[k], -mh1L[r]));
                float l2s = fmaf(a2L[r], x3[k], fmaf(b2L[r], y3[k], -mh2L[r]));
                float e1v = __builtin_amdgcn_exp2f(l1s);
                float e2v = __builtin_amdgcn_exp2f(l2s);
                float gap = fabsf(fmaf(e1v, -cR[r], e2v));
                gt[r] += gap;
                float t = fmaf(l2s, icwFl[r], c0Fl[r]);
                Gpre[r] += (t < 0.f) ? gap : 0.f;
                int fb = (int)t;
                if (t >= 0.f && t < (float)KF) {    // ~0.5% of elements
                    float* HP = r ? hC1 : hC0;
                    float* HG = r ? hC3 : hC2;
                    HP[fb*NT + tid] += e2v;
                    HG[fb*NT + tid] += gap;
                }
            }
        }
    };
    #pragma unroll 1
    for (int it = 0; it < NFULL; ++it) body2(it*NT + tid);
    if (tid < TAILN) body2(NFULL*NT + tid);

    #pragma unroll
    for (int r = 0; r < R; r++) {
        float a = wave_red_sum(gt[r]);
        float b = wave_red_sum(Gpre[r]);
        if (lane == 0) { red[wid*4 + r*2 + 0] = a; red[wid*4 + r*2 + 1] = b; }
    }
    __syncthreads();                                                   // B4

    // ---- Reduce fine histograms: 32 groups x 16 lanes ----
    {
        int grp = tid >> 4, l16 = tid & 15;      // 32 groups
        int isG = grp >> 4;                      // 0: P, 1: G
        int r = (grp >> 3) & 1, b = grp & 7;
        const float* H = isG ? (r ? hC3 : hC2) : (r ? hC1 : hC0);
        float s = 0.f;
        #pragma unroll
        for (int t = 0; t < NT/16; t++) s += H[b*NT + l16 + t*16];
        #pragma unroll
        for (int o = 8; o > 0; o >>= 1) s += __shfl_down(s, o, 64);
        if (l16 == 0) {
            if (isG) shFG[r*KF + b] = s; else shFP[r*KF + b] = s;
        }
    }
    __syncthreads();                                                   // B5

    // ---- Walk fine bins, secant-interpolate 0.5 crossing, output ----
    if (tid < R) {
        const int r = tid;
        float gts = 0, Gp = 0;
        for (int w = 0; w < 8; w++) {
            gts += red[w*4 + r*2 + 0];
            Gp  += red[w*4 + r*2 + 1];
        }
        float thr = shA[r][1], fkl = shA[r][2], rkl = shA[r][3];
        float S = shA[r][6], G = Gp;
        bool done = false;
        #pragma unroll
        for (int i = 0; i < KF; i++) {
            if (!done) {
                float p = shFP[r*KF + i], g = shFG[r*KF + i];
                float ns = S + p;
                if (ns >= thr) {
                    float f = (thr - S) / fmaxf(p, 1e-30f);
                    f = fminf(fmaxf(f, 0.f), 1.f);
                    G += f * g;
                    done = true;
                } else { S = ns; G += g; }
            }
        }
        float gl = G;                    // g_tail (unnormalized: scale cancels)
        float gh = gts - gl;             // g_head
        float akl = (gh*fkl + gl*rkl) / gts;
        unsafeAtomicAdd(out, akl * (1.0f/(float)DNUM));
    }
}

extern "C" void kernel_launch(void* const* d_in, const int* in_sizes, int n_in,
                              void* d_out, int out_size, void* d_ws, size_t ws_size,
                              hipStream_t stream) {
    const float* h1 = (const float*)d_in[0];
    const float* e1 = (const float*)d_in[1];
    const float* h3 = (const float*)d_in[2];
    const float* e3 = (const float*)d_in[3];
    hipMemsetAsync(d_out, 0, sizeof(float), stream);   // capture-safe
    akl_rows<<<GRID, NT, 0, stream>>>(h1, e1, h3, e3, (float*)d_out);
}